// Round 7
// baseline (160.936 us; speedup 1.0000x reference)
//
#include <hip/hip_runtime.h>
#include <hip/hip_bf16.h>
#include <math.h>

#define BB 2
#define SS 2048
#define HH 16
#define DH 64
#define DQK 128
#define DD (HH*DH)
// Q folded scale = (1/sqrt(128)) * log2(e)  -> scores arrive in log2 domain
#define QS2   0.12751758f
// 8 * log2(e): fixed-max bias in log2 domain (cancels exactly in softmax)
#define EBIAS 11.5415605f

typedef _Float16 half8_t __attribute__((ext_vector_type(8)));
typedef _Float16 half4_t __attribute__((ext_vector_type(4)));
typedef float f32x4_t __attribute__((ext_vector_type(4)));
typedef float f32x4v __attribute__((ext_vector_type(4)));

__device__ __forceinline__ void fsincos(float th, float* sn, float* cs) {
  float rev = th * 0.15915494309189535f;
  rev -= floorf(rev);
  float ang = rev * 6.283185307179586f;
  *sn = __sinf(ang);
  *cs = __cosf(ang);
}

// async global->LDS DMA, 16B/lane, LDS dest = uniform base + lane*16
__device__ __forceinline__ void dma16(const void* g, void* l) {
  __builtin_amdgcn_global_load_lds(
      (const __attribute__((address_space(1))) unsigned int*)g,
      (__attribute__((address_space(3))) unsigned int*)l, 16, 0, 0);
}

// Block per (bh, s-tile of 64). Emits (Q is generated inside flash_attn):
//   K  swizzled  [bh][ktile64][d8 0..15][key 0..63] 16B units (d8 = 8-f16 group of dim128)
//   V  swizzled  [bh][ktile64][k8 0..7][dv 0..63]  16B units (8 consecutive keys per unit)
__global__ __launch_bounds__(256) void gen_kv(
    const float* __restrict__ x,
    const float* __restrict__ wk, const float* __restrict__ bk,
    const float* __restrict__ phk,
    const float* __restrict__ wv, const float* __restrict__ bv,
    _Float16* __restrict__ Kd, _Float16* __restrict__ Vtd)
{
  int stile = blockIdx.x & 31;
  int bh    = blockIdx.x >> 5;
  int b = bh >> 4, h = bh & 15;
  int t = threadIdx.x;
  int sl = t >> 2;                 // 0..63 (key/row within tile)
  int dq = (t & 3) << 4;           // 0,16,32,48
  int s  = stile * 64 + sl;

  __shared__ _Float16 Vl[64 * 65]; // transpose buffer, odd pitch

  const float* xr = x + (((size_t)b * SS + s) * HH + h) * DH + dq;
  float xv[16];
#pragma unroll
  for (int i = 0; i < 4; i++)
    *(f32x4v*)(&xv[i * 4]) = *(const f32x4v*)(xr + i * 4);

  float tv = (float)s;
  _Float16 kc[16], ks[16];
#pragma unroll
  for (int i = 0; i < 16; i++) {
    int d = dq + i;
    int hd = h * DH + d;
    {
      float th = xv[i] / (1.f + fabsf(wk[hd])) + bk[hd] + tv * phk[hd];
      float sn, cs; fsincos(th, &sn, &cs);
      kc[i] = (_Float16)cs;
      ks[i] = (_Float16)sn;
    }
    {
      float th = xv[i] / (1.f + fabsf(wv[hd])) + bv[hd];
      float sn, cs; fsincos(th, &sn, &cs);
      Vl[d * 65 + sl] = (_Float16)(cs + sn);
    }
  }
  // K swizzled: cos dims d -> d8 = d/8; sin dims -> d8 = 8 + d/8
  {
    size_t ktb = ((size_t)bh * 32 + stile) * 8192;  // f16 base of 16KB tile
    int fo0 = (t & 3) * 2;
    *(half8_t*)(Kd + ktb + ((size_t)(fo0    ) * 64 + sl) * 8) = *(half8_t*)(&kc[0]);
    *(half8_t*)(Kd + ktb + ((size_t)(fo0 + 1) * 64 + sl) * 8) = *(half8_t*)(&kc[8]);
    *(half8_t*)(Kd + ktb + ((size_t)(fo0 + 8) * 64 + sl) * 8) = *(half8_t*)(&ks[0]);
    *(half8_t*)(Kd + ktb + ((size_t)(fo0 + 9) * 64 + sl) * 8) = *(half8_t*)(&ks[8]);
  }
  __syncthreads();
  // V swizzled: unit (k8, dv) = V[dv][keys k8*8..+7]; 2 units/thread, coalesced
#pragma unroll
  for (int i = 0; i < 2; i++) {
    int u = t * 2 + i;
    int dv = u & 63, ku = u >> 6;    // ku 0..7
    _Float16 tmp[8];
#pragma unroll
    for (int jj = 0; jj < 8; jj++) tmp[jj] = Vl[dv * 65 + ku * 8 + jj];
    *(half8_t*)(Vtd + (((size_t)bh * 32 + stile) * 8 + ku) * 512 + dv * 8) =
        *(half8_t*)tmp;
  }
}

// 512 blocks; bi = j*32 + bh so XCD(bi%8) = bh%8 -> all 16 blocks of a bh share
// one XCD's L2. Block j does q-tiles (31-j),(j): 33 uniform chunks.
// 4 waves = (qh: 32-q half) x (kh: 32-key half). Transposed-S: S^T = mfma(K,Q),
// exp2 in-register, pack -> B-frag of 16x16x16 PV; P never touches LDS.
// Q frags computed in-kernel from x (q-tiles are block-private).
// LDS 48KB (epilogue O-buffer overlays the idle KV half) -> 3 blocks/CU.
__global__ __launch_bounds__(256, 3) void flash_attn(
    const float* __restrict__ x,
    const float* __restrict__ wq, const float* __restrict__ bq,
    const float* __restrict__ phq,
    const _Float16* __restrict__ Kd, const _Float16* __restrict__ Vtd,
    const float* __restrict__ wout, const float* __restrict__ bout,
    float* __restrict__ out)
{
  int j  = blockIdx.x >> 5;          // 0..15  (pair index)
  int bh = blockIdx.x & 31;          // XCD = bh % 8
  int b  = bh >> 4, hh = bh & 15;
  int wave = threadIdx.x >> 6;
  int lane = threadIdx.x & 63;
  int lm = lane & 15, lq = lane >> 4;
  int qh = wave >> 1;
  int kh = wave & 1;

  __shared__ __align__(16) _Float16 KV[2][12288];   // per buf: K 16KB + V 8KB

  const _Float16* Kg = Kd + (size_t)bh * 32 * 8192;
  const _Float16* Vg = Vtd + (size_t)bh * 32 * 4096;

  for (int phase = 0; phase < 2; ++phase) {
    int qt = phase == 0 ? (31 - j) : j;
    int nch = qt + 1;
    int q0 = qt * 64;

    __syncthreads();   // prev-phase epilogue LDS reads done before DMA reuse

    {  // preload chunk 0 -> buf 0 (flies while we build Q frags below)
#pragma unroll
      for (int i = 0; i < 4; i++)
        dma16(Kg + (size_t)(wave * 4 + i) * 512 + lane * 8, &KV[0][(wave * 4 + i) * 512]);
#pragma unroll
      for (int i = 0; i < 2; i++)
        dma16(Vg + (size_t)(wave * 2 + i) * 512 + lane * 8, &KV[0][8192 + (wave * 2 + i) * 512]);
    }

    // Build Q B-frags from x: B[n=q][k=c*32+lq*8+jj]; c0/c1 = cos of dims
    // lq*8.. / 32+lq*8.., c2/c3 = sin of same dims. Scale QS2 folded.
    half8_t aq[2][4];
#pragma unroll
    for (int qtl = 0; qtl < 2; qtl++) {
      int row = q0 + qh * 32 + qtl * 16 + lm;
      const float* xr = x + (((size_t)b * SS + row) * HH + hh) * DH;
      float xv[16];
      *(f32x4v*)(&xv[0])  = *(const f32x4v*)(xr + lq * 8);
      *(f32x4v*)(&xv[4])  = *(const f32x4v*)(xr + lq * 8 + 4);
      *(f32x4v*)(&xv[8])  = *(const f32x4v*)(xr + 32 + lq * 8);
      *(f32x4v*)(&xv[12]) = *(const f32x4v*)(xr + 32 + lq * 8 + 4);
      float trow = (float)row;
      _Float16 qc[16], qs[16];
#pragma unroll
      for (int jj = 0; jj < 16; jj++) {
        int d  = (jj < 8 ? lq * 8 + jj : 32 + lq * 8 + (jj - 8));
        int hd = hh * DH + d;
        float th = xv[jj] / (1.f + fabsf(wq[hd])) + bq[hd] + trow * phq[hd];
        float sn, cs; fsincos(th, &sn, &cs);
        qc[jj] = (_Float16)(cs * QS2);
        qs[jj] = (_Float16)(sn * QS2);
      }
      aq[qtl][0] = *(half8_t*)(&qc[0]);
      aq[qtl][1] = *(half8_t*)(&qc[8]);
      aq[qtl][2] = *(half8_t*)(&qs[0]);
      aq[qtl][3] = *(half8_t*)(&qs[8]);
    }

    f32x4_t o[4][2];   // [dv-tile][q-tile], element = O^T[dt*16+lq*4+r][qtl*16+lm]
    float l[2] = {0.f, 0.f};
#pragma unroll
    for (int dt = 0; dt < 4; dt++)
#pragma unroll
      for (int qtl = 0; qtl < 2; qtl++) o[dt][qtl] = (f32x4_t){0.f, 0.f, 0.f, 0.f};

    for (int kt = 0; kt < nch; ++kt) {
      int bf = kt & 1;
      __syncthreads();   // drains DMA (vmcnt0 before barrier) + compute of kt-1
      if (kt + 1 < nch) {
        int nb = (kt + 1) & 1;
        const _Float16* gK = Kg + (size_t)(kt + 1) * 8192;
        const _Float16* gV = Vg + (size_t)(kt + 1) * 4096;
#pragma unroll
        for (int i = 0; i < 4; i++)
          dma16(gK + (size_t)(wave * 4 + i) * 512 + lane * 8, &KV[nb][(wave * 4 + i) * 512]);
#pragma unroll
        for (int i = 0; i < 2; i++)
          dma16(gV + (size_t)(wave * 2 + i) * 512 + lane * 8, &KV[nb][8192 + (wave * 2 + i) * 512]);
      }

      const _Float16* lK = &KV[bf][0];
      const _Float16* lV = &KV[bf][8192];
      int k0 = kt * 64;

      // S^T = K Q^T : C-layout (key = lq*4+r, q = lm); 2 key-tiles x 2 q-tiles
      f32x4_t cST[2][2];
      cST[0][0] = cST[0][1] = cST[1][0] = cST[1][1] = (f32x4_t){0.f, 0.f, 0.f, 0.f};
#pragma unroll
      for (int c = 0; c < 4; c++) {
        half8_t k0f = *(const half8_t*)(lK + ((size_t)(c * 4 + lq) * 64 + kh * 32 + lm) * 8);
        half8_t k1f = *(const half8_t*)(lK + ((size_t)(c * 4 + lq) * 64 + kh * 32 + 16 + lm) * 8);
        cST[0][0] = __builtin_amdgcn_mfma_f32_16x16x32_f16(k0f, aq[0][c], cST[0][0], 0, 0, 0);
        cST[0][1] = __builtin_amdgcn_mfma_f32_16x16x32_f16(k0f, aq[1][c], cST[0][1], 0, 0, 0);
        cST[1][0] = __builtin_amdgcn_mfma_f32_16x16x32_f16(k1f, aq[0][c], cST[1][0], 0, 0, 0);
        cST[1][1] = __builtin_amdgcn_mfma_f32_16x16x32_f16(k1f, aq[1][c], cST[1][1], 0, 0, 0);
      }

      // p = 2^(s2 - EBIAS) in-register; pack -> B-frags (B[n=q=lm][k=lq*4+i])
      bool maskit = (kt == nch - 1);
      half4_t pb[2][2];
#pragma unroll
      for (int ktl = 0; ktl < 2; ktl++)
#pragma unroll
        for (int qtl = 0; qtl < 2; qtl++) {
          float pf[4];
#pragma unroll
          for (int r = 0; r < 4; r++) {
            float sv = cST[ktl][qtl][r] - EBIAS;
            if (maskit) {
              int key  = k0 + kh * 32 + ktl * 16 + lq * 4 + r;
              int qrow = q0 + qh * 32 + qtl * 16 + lm;
              if (key > qrow) sv = -1e30f;
            }
            pf[r] = __builtin_exp2f(sv);
            l[qtl] += pf[r];
          }
          pb[ktl][qtl] = (half4_t){(_Float16)pf[0], (_Float16)pf[1],
                                   (_Float16)pf[2], (_Float16)pf[3]};
        }

      // O^T += V^T P^T : A = V^T frag (m=dv, k=key lq*4+i), 16 MFMA 16x16x16
#pragma unroll
      for (int dt = 0; dt < 4; dt++)
#pragma unroll
        for (int kg = 0; kg < 2; kg++) {
          half4_t vf = *(const half4_t*)(lV +
              ((size_t)(kh * 4 + kg * 2 + (lq >> 1)) * 64 + dt * 16 + lm) * 8 + (lq & 1) * 4);
          o[dt][0] = __builtin_amdgcn_mfma_f32_16x16x16f16(vf, pb[kg][0], o[dt][0], 0, 0, 0);
          o[dt][1] = __builtin_amdgcn_mfma_f32_16x16x16f16(vf, pb[kg][1], o[dt][1], 0, 0, 0);
        }
    }

    // reduce l over lq groups (keys): all lanes end with l for q = qtl*16+lm
#pragma unroll
    for (int qtl = 0; qtl < 2; qtl++) {
      l[qtl] += __shfl_xor(l[qtl], 16);
      l[qtl] += __shfl_xor(l[qtl], 32);
    }

    // combine kh halves + normalize via LDS overlaid on the idle KV buffer
    // (last chunk used buf (nch-1)&1, so buf nch&1 is free), then epilogue.
    int sc = nch & 1;
    float* Of = (float*)&KV[sc][0];        // [row][pitch 68], 17408 B < 24576 B
    float* Lf = Of + 64 * 68;
    __syncthreads();
    if (kh == 1) {
#pragma unroll
      for (int qtl = 0; qtl < 2; qtl++) {
        int row = qh * 32 + qtl * 16 + lm;
#pragma unroll
        for (int dt = 0; dt < 4; dt++)
#pragma unroll
          for (int r = 0; r < 4; r++)
            Of[row * 68 + dt * 16 + lq * 4 + r] = o[dt][qtl][r];
        if (lq == 0) Lf[row] = l[qtl];
      }
    }
    __syncthreads();
    if (kh == 0) {
#pragma unroll
      for (int qtl = 0; qtl < 2; qtl++) {
        int row = qh * 32 + qtl * 16 + lm;
        float rl = 1.f / (l[qtl] + Lf[row]);
#pragma unroll
        for (int dt = 0; dt < 4; dt++)
#pragma unroll
          for (int r = 0; r < 4; r++) {
            int idx = row * 68 + dt * 16 + lq * 4 + r;
            Of[idx] = (o[dt][qtl][r] + Of[idx]) * rl;
          }
      }
    }
    __syncthreads();
    {
      int dcol = hh * DH + lane;
      float iw = 1.f / (1.f + fabsf(wout[dcol]));
      float bo = bout[dcol];
#pragma unroll
      for (int rr = 0; rr < 16; rr++) {
        int row = wave * 16 + rr;
        float th = Of[row * 68 + lane] * iw + bo;
        float sn, cs; fsincos(th, &sn, &cs);
        out[((size_t)b * SS + q0 + row) * DD + dcol] = cs + sn;
      }
    }
  }
}

extern "C" void kernel_launch(void* const* d_in, const int* in_sizes, int n_in,
                              void* d_out, int out_size, void* d_ws, size_t ws_size,
                              hipStream_t stream) {
  (void)in_sizes; (void)n_in; (void)out_size; (void)ws_size;
  const float* x   = (const float*)d_in[0];
  const float* wq  = (const float*)d_in[1];
  const float* bq  = (const float*)d_in[2];
  const float* phq = (const float*)d_in[3];
  const float* wk  = (const float*)d_in[4];
  const float* bk  = (const float*)d_in[5];
  const float* phk = (const float*)d_in[6];
  const float* wv  = (const float*)d_in[7];
  const float* bv  = (const float*)d_in[8];
  const float* wo  = (const float*)d_in[9];
  const float* bo  = (const float*)d_in[10];

  _Float16* Kd  = (_Float16*)d_ws;
  _Float16* Vtd = Kd + (size_t)BB * HH * SS * DQK;

  gen_kv<<<BB * HH * (SS / 64), 256, 0, stream>>>(
      x, wk, bk, phk, wv, bv, Kd, Vtd);
  flash_attn<<<BB * HH * 16, 256, 0, stream>>>(
      x, wq, bq, phq, Kd, Vtd, wo, bo, (float*)d_out);
}

// Round 8
// 141.301 us; speedup vs baseline: 1.1390x; 1.1390x over previous
//
#include <hip/hip_runtime.h>
#include <hip/hip_bf16.h>
#include <math.h>

#define BB 2
#define SS 2048
#define HH 16
#define DH 64
#define DQK 128
#define DD (HH*DH)
// Q folded scale = (1/sqrt(128)) * log2(e)  -> scores arrive in log2 domain
#define QS2   0.12751758f
// 8 * log2(e): fixed-max bias in log2 domain (cancels exactly in softmax)
#define EBIAS 11.5415605f

typedef _Float16 half8_t __attribute__((ext_vector_type(8)));
typedef _Float16 half4_t __attribute__((ext_vector_type(4)));
typedef float f32x4_t __attribute__((ext_vector_type(4)));
typedef float f32x4v __attribute__((ext_vector_type(4)));

__device__ __forceinline__ void fsincos(float th, float* sn, float* cs) {
  float rev = th * 0.15915494309189535f;
  rev -= floorf(rev);
  float ang = rev * 6.283185307179586f;
  *sn = __sinf(ang);
  *cs = __cosf(ang);
}

// async global->LDS DMA, 16B/lane, LDS dest = uniform base + lane*16
__device__ __forceinline__ void dma16(const void* g, void* l) {
  __builtin_amdgcn_global_load_lds(
      (const __attribute__((address_space(1))) unsigned int*)g,
      (__attribute__((address_space(3))) unsigned int*)l, 16, 0, 0);
}

// Block per (bh, s-tile of 64). Emits:
//   Q  row-major [bh][s][128], scale QS2 folded (log2-domain scores)
//   K  swizzled  [bh][ktile64][d8 0..15][key 0..63] 16B units
//   V  swizzled  [bh][ktile64][k8 0..7][dv 0..63]  16B units
__global__ __launch_bounds__(256) void gen_qkv(
    const float* __restrict__ x,
    const float* __restrict__ wq, const float* __restrict__ bq,
    const float* __restrict__ phq,
    const float* __restrict__ wk, const float* __restrict__ bk,
    const float* __restrict__ phk,
    const float* __restrict__ wv, const float* __restrict__ bv,
    _Float16* __restrict__ Qd, _Float16* __restrict__ Kd, _Float16* __restrict__ Vtd)
{
  int stile = blockIdx.x & 31;
  int bh    = blockIdx.x >> 5;
  int b = bh >> 4, h = bh & 15;
  int t = threadIdx.x;
  int sl = t >> 2;                 // 0..63 (key/row within tile)
  int dq = (t & 3) << 4;           // 0,16,32,48
  int s  = stile * 64 + sl;

  __shared__ _Float16 Vl[64 * 65]; // transpose buffer, odd pitch

  const float* xr = x + (((size_t)b * SS + s) * HH + h) * DH + dq;
  float xv[16];
#pragma unroll
  for (int i = 0; i < 4; i++)
    *(f32x4v*)(&xv[i * 4]) = *(const f32x4v*)(xr + i * 4);

  float tv = (float)s;
  _Float16 qc[16], qs[16], kc[16], ks[16];
#pragma unroll
  for (int i = 0; i < 16; i++) {
    int d = dq + i;
    int hd = h * DH + d;
    {
      float th = xv[i] / (1.f + fabsf(wq[hd])) + bq[hd] + tv * phq[hd];
      float sn, cs; fsincos(th, &sn, &cs);
      qc[i] = (_Float16)(cs * QS2);
      qs[i] = (_Float16)(sn * QS2);
    }
    {
      float th = xv[i] / (1.f + fabsf(wk[hd])) + bk[hd] + tv * phk[hd];
      float sn, cs; fsincos(th, &sn, &cs);
      kc[i] = (_Float16)cs;
      ks[i] = (_Float16)sn;
    }
    {
      float th = xv[i] / (1.f + fabsf(wv[hd])) + bv[hd];
      float sn, cs; fsincos(th, &sn, &cs);
      Vl[d * 65 + sl] = (_Float16)(cs + sn);
    }
  }
  // Q row-major
  size_t qbase = ((size_t)bh * SS + s) * DQK;
#pragma unroll
  for (int i = 0; i < 2; i++) {
    *(half8_t*)(Qd + qbase + dq + i * 8)      = *(half8_t*)(&qc[i * 8]);
    *(half8_t*)(Qd + qbase + DH + dq + i * 8) = *(half8_t*)(&qs[i * 8]);
  }
  // K swizzled: cos dims d -> d8 = d/8; sin dims -> d8 = 8 + d/8
  {
    size_t ktb = ((size_t)bh * 32 + stile) * 8192;  // f16 base of 16KB tile
    int fo0 = (t & 3) * 2;
    *(half8_t*)(Kd + ktb + ((size_t)(fo0    ) * 64 + sl) * 8) = *(half8_t*)(&kc[0]);
    *(half8_t*)(Kd + ktb + ((size_t)(fo0 + 1) * 64 + sl) * 8) = *(half8_t*)(&kc[8]);
    *(half8_t*)(Kd + ktb + ((size_t)(fo0 + 8) * 64 + sl) * 8) = *(half8_t*)(&ks[0]);
    *(half8_t*)(Kd + ktb + ((size_t)(fo0 + 9) * 64 + sl) * 8) = *(half8_t*)(&ks[8]);
  }
  __syncthreads();
  // V swizzled: unit (k8, dv) = V[dv][keys k8*8..+7]; 2 units/thread, coalesced
#pragma unroll
  for (int i = 0; i < 2; i++) {
    int u = t * 2 + i;
    int dv = u & 63, ku = u >> 6;    // ku 0..7
    _Float16 tmp[8];
#pragma unroll
    for (int jj = 0; jj < 8; jj++) tmp[jj] = Vl[dv * 65 + ku * 8 + jj];
    *(half8_t*)(Vtd + (((size_t)bh * 32 + stile) * 8 + ku) * 512 + dv * 8) =
        *(half8_t*)tmp;
  }
}

// 1024 blocks = 32 qt x 32 bh, one q-tile each. qt = 31 - (bi>>5): heaviest
// blocks dispatch first (LPT) so backfill evens the causal triangle.
// bh = bi & 31 -> XCD(bi%8) = bh%8: K/V of a bh stay on one XCD's L2.
// 4 waves = (qh: 32-q half) x (kh: 32-key half). Transposed-S: S^T = mfma(K,Q)
// with acc preloaded to -EBIAS, exp2 in-register, pack -> B-frag of 16x16x16
// PV MFMA; P never touches LDS. LDS 48KB (epilogue overlays idle KV buffer)
// -> 3 blocks/CU. No launch_bounds min-wave (R7 lesson: forcing it spills).
__global__ __launch_bounds__(256) void flash_attn(
    const _Float16* __restrict__ Qd, const _Float16* __restrict__ Kd,
    const _Float16* __restrict__ Vtd,
    const float* __restrict__ wout, const float* __restrict__ bout,
    float* __restrict__ out)
{
  int qt = 31 - (blockIdx.x >> 5);
  int bh = blockIdx.x & 31;          // XCD = bh % 8
  int b  = bh >> 4, hh = bh & 15;
  int nch = qt + 1;
  int q0 = qt * 64;
  int wave = threadIdx.x >> 6;
  int lane = threadIdx.x & 63;
  int lm = lane & 15, lq = lane >> 4;
  int qh = wave >> 1;
  int kh = wave & 1;

  __shared__ __align__(16) _Float16 KV[2][12288];   // per buf: K 16KB + V 8KB

  const _Float16* Kg = Kd + (size_t)bh * 32 * 8192;
  const _Float16* Vg = Vtd + (size_t)bh * 32 * 4096;

  {  // preload chunk 0 -> buf 0 (flies while Q frags load below)
#pragma unroll
    for (int i = 0; i < 4; i++)
      dma16(Kg + (size_t)(wave * 4 + i) * 512 + lane * 8, &KV[0][(wave * 4 + i) * 512]);
#pragma unroll
    for (int i = 0; i < 2; i++)
      dma16(Vg + (size_t)(wave * 2 + i) * 512 + lane * 8, &KV[0][8192 + (wave * 2 + i) * 512]);
  }

  // Q B-frags resident: B[n=q][k=c*32+lq*8+j]
  const _Float16* Qb = Qd + ((size_t)bh * SS + q0 + qh * 32) * DQK;
  half8_t aq[2][4];
#pragma unroll
  for (int qtl = 0; qtl < 2; qtl++)
#pragma unroll
    for (int c = 0; c < 4; c++)
      aq[qtl][c] = *(const half8_t*)(Qb + (qtl * 16 + lm) * DQK + c * 32 + lq * 8);

  f32x4_t o[4][2];   // [dv-tile][q-tile], element = O^T[dt*16+lq*4+r][qtl*16+lm]
  float l[2] = {0.f, 0.f};
#pragma unroll
  for (int dt = 0; dt < 4; dt++)
#pragma unroll
    for (int qtl = 0; qtl < 2; qtl++) o[dt][qtl] = (f32x4_t){0.f, 0.f, 0.f, 0.f};

  const f32x4_t cinit = (f32x4_t){-EBIAS, -EBIAS, -EBIAS, -EBIAS};

  for (int kt = 0; kt < nch; ++kt) {
    int bf = kt & 1;
    __syncthreads();   // drains DMA (vmcnt0 before barrier) + compute of kt-1
    if (kt + 1 < nch) {
      int nb = (kt + 1) & 1;
      const _Float16* gK = Kg + (size_t)(kt + 1) * 8192;
      const _Float16* gV = Vg + (size_t)(kt + 1) * 4096;
#pragma unroll
      for (int i = 0; i < 4; i++)
        dma16(gK + (size_t)(wave * 4 + i) * 512 + lane * 8, &KV[nb][(wave * 4 + i) * 512]);
#pragma unroll
      for (int i = 0; i < 2; i++)
        dma16(gV + (size_t)(wave * 2 + i) * 512 + lane * 8, &KV[nb][8192 + (wave * 2 + i) * 512]);
    }

    const _Float16* lK = &KV[bf][0];
    const _Float16* lV = &KV[bf][8192];
    int k0 = kt * 64;

    // S^T - EBIAS = K Q^T + (-EBIAS) : C-layout (key = lq*4+r, q = lm)
    f32x4_t cST[2][2];
    cST[0][0] = cST[0][1] = cST[1][0] = cST[1][1] = cinit;
#pragma unroll
    for (int c = 0; c < 4; c++) {
      half8_t k0f = *(const half8_t*)(lK + ((size_t)(c * 4 + lq) * 64 + kh * 32 + lm) * 8);
      half8_t k1f = *(const half8_t*)(lK + ((size_t)(c * 4 + lq) * 64 + kh * 32 + 16 + lm) * 8);
      cST[0][0] = __builtin_amdgcn_mfma_f32_16x16x32_f16(k0f, aq[0][c], cST[0][0], 0, 0, 0);
      cST[0][1] = __builtin_amdgcn_mfma_f32_16x16x32_f16(k0f, aq[1][c], cST[0][1], 0, 0, 0);
      cST[1][0] = __builtin_amdgcn_mfma_f32_16x16x32_f16(k1f, aq[0][c], cST[1][0], 0, 0, 0);
      cST[1][1] = __builtin_amdgcn_mfma_f32_16x16x32_f16(k1f, aq[1][c], cST[1][1], 0, 0, 0);
    }

    // p = 2^(s2) in-register; pack -> B-frags (B[n=q=lm][k=lq*4+i])
    bool maskit = (kt == nch - 1);
    half4_t pb[2][2];
#pragma unroll
    for (int ktl = 0; ktl < 2; ktl++)
#pragma unroll
      for (int qtl = 0; qtl < 2; qtl++) {
        float pf[4];
#pragma unroll
        for (int r = 0; r < 4; r++) {
          float sv = cST[ktl][qtl][r];
          if (maskit) {
            int key  = k0 + kh * 32 + ktl * 16 + lq * 4 + r;
            int qrow = q0 + qh * 32 + qtl * 16 + lm;
            if (key > qrow) sv = -1e30f;
          }
          pf[r] = __builtin_exp2f(sv);
          l[qtl] += pf[r];
        }
        pb[ktl][qtl] = (half4_t){(_Float16)pf[0], (_Float16)pf[1],
                                 (_Float16)pf[2], (_Float16)pf[3]};
      }

    // O^T += V^T P^T : A = V^T frag (m=dv, k=key lq*4+i), 16 MFMA 16x16x16
#pragma unroll
    for (int dt = 0; dt < 4; dt++)
#pragma unroll
      for (int kg = 0; kg < 2; kg++) {
        half4_t vf = *(const half4_t*)(lV +
            ((size_t)(kh * 4 + kg * 2 + (lq >> 1)) * 64 + dt * 16 + lm) * 8 + (lq & 1) * 4);
        o[dt][0] = __builtin_amdgcn_mfma_f32_16x16x16f16(vf, pb[kg][0], o[dt][0], 0, 0, 0);
        o[dt][1] = __builtin_amdgcn_mfma_f32_16x16x16f16(vf, pb[kg][1], o[dt][1], 0, 0, 0);
      }
  }

  // reduce l over lq groups (keys): all lanes end with l for q = qtl*16+lm
#pragma unroll
  for (int qtl = 0; qtl < 2; qtl++) {
    l[qtl] += __shfl_xor(l[qtl], 16);
    l[qtl] += __shfl_xor(l[qtl], 32);
  }

  // combine kh halves + normalize via LDS overlaid on the idle KV buffer
  // (last chunk used buf (nch-1)&1, so buf nch&1 is free), then epilogue.
  int sc = nch & 1;
  float* Of = (float*)&KV[sc][0];        // [row][pitch 68], 17664 B < 24576 B
  float* Lf = Of + 64 * 68;
  __syncthreads();
  if (kh == 1) {
#pragma unroll
    for (int qtl = 0; qtl < 2; qtl++) {
      int row = qh * 32 + qtl * 16 + lm;
#pragma unroll
      for (int dt = 0; dt < 4; dt++)
#pragma unroll
        for (int r = 0; r < 4; r++)
          Of[row * 68 + dt * 16 + lq * 4 + r] = o[dt][qtl][r];
      if (lq == 0) Lf[row] = l[qtl];
    }
  }
  __syncthreads();
  if (kh == 0) {
#pragma unroll
    for (int qtl = 0; qtl < 2; qtl++) {
      int row = qh * 32 + qtl * 16 + lm;
      float rl = 1.f / (l[qtl] + Lf[row]);
#pragma unroll
      for (int dt = 0; dt < 4; dt++)
#pragma unroll
        for (int r = 0; r < 4; r++) {
          int idx = row * 68 + dt * 16 + lq * 4 + r;
          Of[idx] = (o[dt][qtl][r] + Of[idx]) * rl;
        }
    }
  }
  __syncthreads();
  {
    int dcol = hh * DH + lane;
    float iw = 1.f / (1.f + fabsf(wout[dcol]));
    float bo = bout[dcol];
#pragma unroll
    for (int rr = 0; rr < 16; rr++) {
      int row = wave * 16 + rr;
      float th = Of[row * 68 + lane] * iw + bo;
      float sn, cs; fsincos(th, &sn, &cs);
      out[((size_t)b * SS + q0 + row) * DD + dcol] = cs + sn;
    }
  }
}

extern "C" void kernel_launch(void* const* d_in, const int* in_sizes, int n_in,
                              void* d_out, int out_size, void* d_ws, size_t ws_size,
                              hipStream_t stream) {
  (void)in_sizes; (void)n_in; (void)out_size; (void)ws_size;
  const float* x   = (const float*)d_in[0];
  const float* wq  = (const float*)d_in[1];
  const float* bq  = (const float*)d_in[2];
  const float* phq = (const float*)d_in[3];
  const float* wk  = (const float*)d_in[4];
  const float* bk  = (const float*)d_in[5];
  const float* phk = (const float*)d_in[6];
  const float* wv  = (const float*)d_in[7];
  const float* bv  = (const float*)d_in[8];
  const float* wo  = (const float*)d_in[9];
  const float* bo  = (const float*)d_in[10];

  _Float16* Qd  = (_Float16*)d_ws;
  _Float16* Kd  = Qd + (size_t)BB * HH * SS * DQK;
  _Float16* Vtd = Kd + (size_t)BB * HH * SS * DQK;

  gen_qkv<<<BB * HH * (SS / 64), 256, 0, stream>>>(
      x, wq, bq, phq, wk, bk, phk, wv, bv, Qd, Kd, Vtd);
  flash_attn<<<32 * 32, 256, 0, stream>>>(
      Qd, Kd, Vtd, wo, bo, (float*)d_out);
}